// Round 11
// baseline (383.053 us; speedup 1.0000x reference)
//
#include <hip/hip_runtime.h>
#include <hip/hip_bf16.h>
#include <stdint.h>

#define B_ 2
#define S_ 2048
#define D_ 1024
#define H_ 16
#define HD_ 64
#define KJL 32
#define N3 3072
#define N2 2048

typedef __attribute__((ext_vector_type(8))) __bf16 bf16x8;
typedef __attribute__((ext_vector_type(4))) float floatx4;
typedef __attribute__((ext_vector_type(4))) short short4v;
typedef __attribute__((ext_vector_type(2))) unsigned int uint2v;

__device__ __forceinline__ unsigned short f2b(float x) {
  union { float f; unsigned u; } v; v.f = x;
  unsigned r = v.u + 0x7fffu + ((v.u >> 16) & 1u);
  return (unsigned short)(r >> 16);
}

// pack two floats to packed bf16 (round via +0x8000): hi<<16 | lo
__device__ __forceinline__ unsigned int pkbf(float lo, float hi) {
  union { float f; unsigned u; } a, b;
  a.f = lo; b.f = hi;
  return __builtin_amdgcn_perm(b.u + 0x8000u, a.u + 0x8000u, 0x07060302u);
}

__device__ __forceinline__ void async16(const void* g, void* l) {
  __builtin_amdgcn_global_load_lds((__attribute__((address_space(1))) void*)(g),
                                   (__attribute__((address_space(3))) void*)(l),
                                   16, 0, 0);
}

// ---------------- fused prep: cvt4 | tcvt(V cols) | tcvt(W_proj) | wjl | cnt-zero ----------------
__global__ __launch_bounds__(256)
void prep_kernel(const float* __restrict__ hidden, unsigned short* __restrict__ hB,
                 const float* __restrict__ W_attn, const float* __restrict__ b_attn,
                 const float* __restrict__ Sp, const float* __restrict__ W_proj,
                 unsigned short* __restrict__ Bt2, unsigned short* __restrict__ WpT,
                 float* __restrict__ bias2, unsigned* __restrict__ cnt) {
  __shared__ float shmem[2048];
  const int bid = blockIdx.x;
  const int tid = threadIdx.x;

  if (bid < 512) {                      // ---- cvt4: hidden -> hB ----
    const int n4 = (B_ * S_ * D_) / 4;
    int i = bid * 256 + tid;
    for (; i < n4; i += 512 * 256) {
      float4 v = *(const float4*)(hidden + 4 * (size_t)i);
      short4v o = {(short)f2b(v.x), (short)f2b(v.y), (short)f2b(v.z), (short)f2b(v.w)};
      *(short4v*)(hB + 4 * (size_t)i) = o;
    }
  } else if (bid < 2560) {              // ---- tcvt: 32x32 transpose-convert tiles ----
    const float* in;
    unsigned short* out;
    int Cs, local;
    if (bid < 1536) { local = bid - 512;  in = W_attn + 2048; out = Bt2 + 1024 * 1024; Cs = N3; }
    else            { local = bid - 1536; in = W_proj;        out = WpT;               Cs = D_; }
    float (*t)[33] = (float(*)[33])shmem;
    int c0 = (local & 31) * 32, r0 = (local >> 5) * 32;
    int tx = tid & 31, ty = tid >> 5;
    for (int j = 0; j < 32; j += 8)
      t[ty + j][tx] = in[(size_t)(r0 + ty + j) * Cs + c0 + tx];
    __syncthreads();
    for (int j = 0; j < 32; j += 8)
      out[(size_t)(c0 + ty + j) * D_ + r0 + tx] = f2b(t[tx][ty + j]);
  } else if (bid < 2688) {              // ---- wjl: fused JL weights ----
    const int lb = bid - 2560;          // 0..127
    const int part = lb >> 6;           // 0 = Q, 1 = K
    const int h = (lb >> 2) & 15;
    const int dc = lb & 3;
    for (int i = tid; i < 32 * 64; i += 256) shmem[i] = Sp[i];
    __syncthreads();
    const float scale = part ? 1.0f : 0.125f * 1.44269504f;
    const int d = dc * 256 + tid;
    float w[64];
    const float* src = W_attn + (size_t)d * N3 + part * D_ + h * 64;
    for (int j = 0; j < 16; ++j) {
      float4 v = *(const float4*)&src[j * 4];
      w[j * 4 + 0] = v.x; w[j * 4 + 1] = v.y; w[j * 4 + 2] = v.z; w[j * 4 + 3] = v.w;
    }
    const int nbase = part * 512 + h * 32;
    for (int kjl = 0; kjl < 32; ++kjl) {
      float acc = 0.f;
      for (int hd = 0; hd < 64; ++hd) acc += w[hd] * shmem[kjl * 64 + hd];
      Bt2[(size_t)(nbase + kjl) * D_ + d] = f2b(acc * scale);
    }
    if (dc == 0 && tid < 32) {
      float acc = 0.f;
      for (int hd = 0; hd < 64; ++hd) acc += b_attn[part * D_ + h * 64 + hd] * shmem[tid * 64 + hd];
      bias2[nbase + tid] = acc * scale;
    }
  } else {                              // ---- zero split-K merge counters (re-done every call) ----
    int i = (bid - 2688) * 256 + tid;
    if (i < 2048) cnt[i] = 0u;
  }
}

// ---------------- fused qkv+JL GEMM: 128x128 tiles, BK=64 ----------------
__global__ __launch_bounds__(256, 2)
void qkv2_gemm_kernel(const unsigned short* __restrict__ A,
                      const unsigned short* __restrict__ Bt,
                      const float* __restrict__ b_attn,
                      const float* __restrict__ bias2,
                      unsigned short* __restrict__ Qjl,
                      unsigned short* __restrict__ Kjl,
                      unsigned short* __restrict__ Vc) {
  __shared__ __align__(16) unsigned short As[2][128 * 32];
  __shared__ __align__(16) unsigned short Bs[2][128 * 32];
  const int tid = threadIdx.x;
  const int lane = tid & 63, wv = tid >> 6;
  const int quad = lane >> 4, col = lane & 15;
  const int wm = wv >> 1, wn = wv & 1;
  const int m0 = blockIdx.y * 128, n0 = blockIdx.x * 128;

  floatx4 acc[4][4] = {};

  for (int kk = 0; kk < D_; kk += 64) {
    for (int it = 0; it < 4; ++it) {
      int c = it * 256 + tid;            // 0..1023
      int ks = c >> 9, row = (c >> 2) & 127, kc = c & 3;
      async16(A + (size_t)(m0 + row) * D_ + kk + ks * 32 + kc * 8,
              (unsigned short*)As + c * 8);
    }
    for (int it = 0; it < 4; ++it) {
      int c = it * 256 + tid;
      int ks = c >> 9, row = (c >> 2) & 127, kc = c & 3;
      async16(Bt + (size_t)(n0 + row) * D_ + kk + ks * 32 + kc * 8,
              (unsigned short*)Bs + c * 8);
    }
    asm volatile("s_waitcnt vmcnt(0)" ::: "memory");
    __syncthreads();
    for (int ks = 0; ks < 2; ++ks) {
      bf16x8 af[4], bfr[4];
      for (int mt = 0; mt < 4; ++mt)
        af[mt] = *(const bf16x8*)&As[ks][(wm * 64 + mt * 16 + col) * 32 + quad * 8];
      for (int nt = 0; nt < 4; ++nt)
        bfr[nt] = *(const bf16x8*)&Bs[ks][(wn * 64 + nt * 16 + col) * 32 + quad * 8];
      for (int mt = 0; mt < 4; ++mt)
        for (int nt = 0; nt < 4; ++nt)
          acc[mt][nt] = __builtin_amdgcn_mfma_f32_16x16x32_bf16(
              af[mt], bfr[nt], acc[mt][nt], 0, 0, 0);
    }
    __syncthreads();
  }

  const int pq = n0 >> 9;  // 0=Q, 1=K, >=2 -> V
  for (int mt = 0; mt < 4; ++mt) {
    int gm0 = m0 + wm * 64 + mt * 16 + quad * 4;
    int b = gm0 >> 11, s = gm0 & (S_ - 1);
    for (int nt = 0; nt < 4; ++nt) {
      int gn = n0 + wn * 64 + nt * 16 + col;
      if (pq >= 2) {
        int vcol = gn - 1024;
        float bs = b_attn[2048 + vcol];
        int h = vcol >> 6, hd = vcol & 63;
        short4v vv;
        for (int i = 0; i < 4; ++i)
          vv[i] = (short)f2b(acc[mt][nt][i] + bs);
        size_t idx = ((((size_t)(b * H_ + h) * 64 + (s >> 5)) * 64 + hd) * 32 + (s & 31));
        *(short4v*)&Vc[idx] = vv;
      } else {
        float bs = bias2[gn];
        int gl = gn & 511;
        int h = gl >> 5, kjl = gl & 31;
        unsigned short* dst = pq ? Kjl : Qjl;
        size_t base = ((size_t)(b * H_ + h) * S_ + s) * KJL + kjl;
        for (int i = 0; i < 4; ++i)
          dst[base + (size_t)i * KJL] = f2b(acc[mt][nt][i] + bs);
      }
    }
  }
}

// ---------------- split-2 flash attention with fused last-arriver merge ----------------
// Fixed-max softmax => partials are additive. Each wave writes its partial to Part,
// device fence + per-tile atomic; the SECOND arriver reads only the OTHER half
// (own half still in registers), merges, normalizes, writes AO. No merge kernel.
// DO NOT set launch_bounds min-waves to 4 (round 8: VGPR capped 64 -> 415 MB spills).
// NO runtime-indexed register arrays (round 5 lesson).
__global__ __launch_bounds__(256, 2)
void attn_kernel(const unsigned short* __restrict__ Qjl,
                 const unsigned short* __restrict__ Kjl,
                 const unsigned short* __restrict__ Vc,
                 float* __restrict__ Part,
                 unsigned* __restrict__ cnt,
                 unsigned short* __restrict__ AO) {
  __shared__ __align__(16) unsigned short Ps[4][32 * 136];  // wave-private strips
  const int tid = threadIdx.x;
  const int lane = tid & 63, wv = tid >> 6;
  const int quad = lane >> 4, l15 = lane & 15;

  const int blk = blockIdx.x;            // 0..1023
  const int bh = blk & 31;               // bh ≡ xcd (mod 8): L2 locality
  const int g0 = (blk >> 5) & 7;
  const int half = (blk >> 8) & 1;
  const int g = (blk & 512) ? (15 - g0) : g0;
  const int t = 63 - (g * 4 + wv);       // q-tile: rows t*32..t*32+31

  unsigned short* Pw = &Ps[wv][0];
  const int lastc = t >> 2;
  const int nch = lastc + 1;
  const int kb = half ? ((nch + 1) >> 1) : 0;
  const int ke = half ? nch : ((nch + 1) >> 1);
  const int r = t & 3;

  const int laneK = l15 * KJL + quad * 8;
  const int laneV = l15 * 32 + quad * 8;
  const unsigned short* Kp = Kjl + (size_t)bh * S_ * KJL + laneK + (size_t)kb * 128 * KJL;
  const unsigned short* Vp = Vc + (size_t)bh * (64 * 64 * 32) + laneV + (size_t)kb * 8192;

  bf16x8 aq[2];
  for (int qn = 0; qn < 2; ++qn)
    aq[qn] = *(const bf16x8*)&Qjl[(size_t)(bh * S_ + t * 32 + qn * 16 + l15) * KJL + quad * 8];

  floatx4 o[4][2] = {};
  floatx4 psum[2] = {};
  const floatx4 zz = {0.f, 0.f, 0.f, 0.f};

  for (int kt = kb; kt < ke; ++kt) {
    bf16x8 ak[8];
    for (int sm = 0; sm < 8; ++sm)
      ak[sm] = *(const bf16x8*)&Kp[sm * (16 * KJL)];
    bf16x8 bv[4][4];
    for (int ks = 0; ks < 4; ++ks)
      for (int md = 0; md < 4; ++md)
        bv[ks][md] = *(const bf16x8*)&Vp[ks * 2048 + md * 512];
    Kp += 128 * KJL;
    Vp += 8192;

    floatx4 sc[8][2];
    for (int sm = 0; sm < 8; ++sm)
      for (int qn = 0; qn < 2; ++qn)
        sc[sm][qn] = __builtin_amdgcn_mfma_f32_16x16x32_bf16(ak[sm], aq[qn], zz, 0, 0, 0);

    if (kt == lastc) {                   // causal mask within final chunk
      for (int qn = 0; qn < 2; ++qn) {
        int qloc = r * 32 + qn * 16 + l15;
        for (int sm = 0; sm < 8; ++sm)
          for (int i = 0; i < 4; ++i)
            if (sm * 16 + quad * 4 + i > qloc) sc[sm][qn][i] = -1e30f;
      }
    }

    for (int qn = 0; qn < 2; ++qn) {
      for (int sm = 0; sm < 8; ++sm) {
        float p0 = __builtin_amdgcn_exp2f(sc[sm][qn][0]);
        float p1 = __builtin_amdgcn_exp2f(sc[sm][qn][1]);
        float p2 = __builtin_amdgcn_exp2f(sc[sm][qn][2]);
        float p3 = __builtin_amdgcn_exp2f(sc[sm][qn][3]);
        psum[qn][0] += p0; psum[qn][1] += p1;
        psum[qn][2] += p2; psum[qn][3] += p3;
        uint2v pk2 = {pkbf(p0, p1), pkbf(p2, p3)};
        *(uint2v*)&Pw[(qn * 16 + l15) * 136 + sm * 16 + quad * 4] = pk2;
      }
    }

    for (int ks = 0; ks < 4; ++ks) {
      bf16x8 bp[2];
      for (int qn = 0; qn < 2; ++qn)
        bp[qn] = *(const bf16x8*)&Pw[(qn * 16 + l15) * 136 + ks * 32 + quad * 8];
      for (int qn = 0; qn < 2; ++qn)
        for (int md = 0; md < 4; ++md)
          o[md][qn] = __builtin_amdgcn_mfma_f32_16x16x32_bf16(bv[ks][md], bp[qn], o[md][qn], 0, 0, 0);
    }
  }

  // ---- partial epilogue: reduce row sums, publish partial ----
  float l0 = psum[0][0] + psum[0][1] + psum[0][2] + psum[0][3];
  float l1 = psum[1][0] + psum[1][1] + psum[1][2] + psum[1][3];
  l0 += __shfl_xor(l0, 16, 64); l0 += __shfl_xor(l0, 32, 64);
  l1 += __shfl_xor(l1, 16, 64); l1 += __shfl_xor(l1, 32, 64);

  const int tile = bh * 64 + t;
  float* Pp = Part + ((size_t)(tile * 2 + half) * 9 * 64 + lane) * 4;
  for (int qn = 0; qn < 2; ++qn)
    for (int md = 0; md < 4; ++md)
      *(floatx4*)(Pp + (size_t)(qn * 4 + md) * 256) = o[md][qn];
  floatx4 lv = {l0, l1, 0.f, 0.f};
  *(floatx4*)(Pp + (size_t)8 * 256) = lv;

  // ---- last-arriver merge (device-scope fence + atomic; XCD-safe) ----
  __threadfence();
  unsigned old = 0;
  if ((lane & 63) == 0) old = atomicAdd(&cnt[tile], 1u);
  old = __shfl((int)old, 0, 64);
  if (old == 1) {
    __threadfence();  // acquire: other half's Part writes now visible
    const float* Po = Part + ((size_t)(tile * 2 + (half ^ 1)) * 9 * 64 + lane) * 4;
    floatx4 lo = *(const floatx4*)(Po + (size_t)8 * 256);
    float inv0 = 1.f / (l0 + lo[0]);
    float inv1 = 1.f / (l1 + lo[1]);
    for (int qn = 0; qn < 2; ++qn) {
      float inv = qn ? inv1 : inv0;
      for (int md = 0; md < 4; ++md) {
        floatx4 a = *(const floatx4*)(Po + (size_t)(qn * 4 + md) * 256);
        floatx4 s0 = o[md][qn];
        uint2v t4 = {pkbf((s0[0] + a[0]) * inv, (s0[1] + a[1]) * inv),
                     pkbf((s0[2] + a[2]) * inv, (s0[3] + a[3]) * inv)};
        *(uint2v*)&Pw[(qn * 16 + l15) * 72 + md * 16 + quad * 4] = t4;
      }
    }
    asm volatile("s_waitcnt lgkmcnt(0)" ::: "memory");
    const int b = bh >> 4, h = bh & 15;
    int q = lane >> 1, hf = lane & 1;
    size_t gbase = ((size_t)(b * S_ + t * 32 + q)) * D_ + h * HD_ + hf * 32;
    for (int jj = 0; jj < 4; ++jj) {
      bf16x8 v = *(const bf16x8*)&Pw[q * 72 + hf * 32 + jj * 8];
      *(bf16x8*)&AO[gbase + jj * 8] = v;
    }
  }
}

// ---------------- output projection: 64x128 tiles, BK=64 ----------------
__global__ __launch_bounds__(256, 2)
void proj_gemm_kernel(const unsigned short* __restrict__ A,
                      const unsigned short* __restrict__ Bt,
                      const float* __restrict__ bias,
                      float* __restrict__ out) {
  __shared__ __align__(16) unsigned short As[2][64 * 32];
  __shared__ __align__(16) unsigned short Bs[2][128 * 32];
  const int tid = threadIdx.x;
  const int lane = tid & 63, wv = tid >> 6;
  const int quad = lane >> 4, col = lane & 15;
  const int wm = wv >> 1, wn = wv & 1;
  const int m0 = blockIdx.y * 64, n0 = blockIdx.x * 128;

  floatx4 acc[2][4] = {};

  for (int kk = 0; kk < D_; kk += 64) {
    for (int it = 0; it < 2; ++it) {     // A: 64 rows x 64 k = 512 chunks
      int c = it * 256 + tid;
      int ks = c >> 8, row = (c >> 2) & 63, kc = c & 3;
      async16(A + (size_t)(m0 + row) * D_ + kk + ks * 32 + kc * 8,
              (unsigned short*)As + c * 8);
    }
    for (int it = 0; it < 4; ++it) {     // B: 128 rows x 64 k = 1024 chunks
      int c = it * 256 + tid;
      int ks = c >> 9, row = (c >> 2) & 127, kc = c & 3;
      async16(Bt + (size_t)(n0 + row) * D_ + kk + ks * 32 + kc * 8,
              (unsigned short*)Bs + c * 8);
    }
    asm volatile("s_waitcnt vmcnt(0)" ::: "memory");
    __syncthreads();
    for (int ks = 0; ks < 2; ++ks) {
      bf16x8 af[2], bfr[4];
      for (int mt = 0; mt < 2; ++mt)
        af[mt] = *(const bf16x8*)&As[ks][(wm * 32 + mt * 16 + col) * 32 + quad * 8];
      for (int nt = 0; nt < 4; ++nt)
        bfr[nt] = *(const bf16x8*)&Bs[ks][(wn * 64 + nt * 16 + col) * 32 + quad * 8];
      for (int mt = 0; mt < 2; ++mt)
        for (int nt = 0; nt < 4; ++nt)
          acc[mt][nt] = __builtin_amdgcn_mfma_f32_16x16x32_bf16(
              af[mt], bfr[nt], acc[mt][nt], 0, 0, 0);
    }
    __syncthreads();
  }

  for (int mt = 0; mt < 2; ++mt) {
    int gm0 = m0 + wm * 32 + mt * 16 + quad * 4;
    for (int nt = 0; nt < 4; ++nt) {
      int gn = n0 + wn * 64 + nt * 16 + col;
      float bs = bias[gn];
      for (int i = 0; i < 4; ++i)
        out[(size_t)(gm0 + i) * D_ + gn] = acc[mt][nt][i] + bs;
    }
  }
}

extern "C" void kernel_launch(void* const* d_in, const int* in_sizes, int n_in,
                              void* d_out, int out_size, void* d_ws, size_t ws_size,
                              hipStream_t stream) {
  (void)in_sizes; (void)n_in; (void)out_size; (void)ws_size;
  const float* hidden = (const float*)d_in[0];
  const float* W_attn = (const float*)d_in[1];
  const float* b_attn = (const float*)d_in[2];
  const float* S_proj = (const float*)d_in[3];
  const float* W_proj = (const float*)d_in[4];
  const float* b_proj = (const float*)d_in[5];
  float* out = (float*)d_out;

  char* ws = (char*)d_ws;
  unsigned short* hB    = (unsigned short*)(ws);                    //  8 MB
  unsigned short* Bt2   = (unsigned short*)(ws + (8u << 20));       //  4 MB
  unsigned short* WpT   = (unsigned short*)(ws + (12u << 20));      //  2 MB
  float*          bias2 = (float*)         (ws + (14u << 20));      //  4 KB
  unsigned short* Qjl   = (unsigned short*)(ws + (15u << 20));      //  4 MB
  unsigned short* Kjl   = (unsigned short*)(ws + (19u << 20));      //  4 MB
  unsigned short* Vc    = (unsigned short*)(ws + (23u << 20));      //  8 MB
  unsigned short* AO    = (unsigned short*)(ws + (31u << 20));      //  8 MB
  float*          Part  = (float*)         (ws + (40u << 20));      // 38 MB
  unsigned*       cnt   = (unsigned*)      (ws + (79u << 20));      //  8 KB

  prep_kernel<<<2696, 256, 0, stream>>>(hidden, hB, W_attn, b_attn, S_proj,
                                        W_proj, Bt2, WpT, bias2, cnt);
  qkv2_gemm_kernel<<<dim3(N2 / 128, (B_ * S_) / 128), 256, 0, stream>>>(
      hB, Bt2, b_attn, bias2, Qjl, Kjl, Vc);
  attn_kernel<<<1024, 256, 0, stream>>>(Qjl, Kjl, Vc, Part, cnt, AO);
  proj_gemm_kernel<<<dim3(D_ / 128, (B_ * S_) / 64), 256, 0, stream>>>(
      AO, WpT, b_proj, out);
}

// Round 12
// 182.899 us; speedup vs baseline: 2.0943x; 2.0943x over previous
//
#include <hip/hip_runtime.h>
#include <hip/hip_bf16.h>
#include <stdint.h>

#define B_ 2
#define S_ 2048
#define D_ 1024
#define H_ 16
#define HD_ 64
#define KJL 32
#define N3 3072
#define N2 2048

typedef __attribute__((ext_vector_type(8))) __bf16 bf16x8;
typedef __attribute__((ext_vector_type(4))) float floatx4;
typedef __attribute__((ext_vector_type(4))) short short4v;
typedef __attribute__((ext_vector_type(2))) unsigned int uint2v;

__device__ __forceinline__ unsigned short f2b(float x) {
  union { float f; unsigned u; } v; v.f = x;
  unsigned r = v.u + 0x7fffu + ((v.u >> 16) & 1u);
  return (unsigned short)(r >> 16);
}

// pack two floats to packed bf16 (round via +0x8000): hi<<16 | lo
__device__ __forceinline__ unsigned int pkbf(float lo, float hi) {
  union { float f; unsigned u; } a, b;
  a.f = lo; b.f = hi;
  return __builtin_amdgcn_perm(b.u + 0x8000u, a.u + 0x8000u, 0x07060302u);
}

__device__ __forceinline__ void async16(const void* g, void* l) {
  __builtin_amdgcn_global_load_lds((__attribute__((address_space(1))) void*)(g),
                                   (__attribute__((address_space(3))) void*)(l),
                                   16, 0, 0);
}

// ---------------- fused prep: cvt4 | tcvt(V cols) | tcvt(W_proj) | wjl ----------------
__global__ __launch_bounds__(256)
void prep_kernel(const float* __restrict__ hidden, unsigned short* __restrict__ hB,
                 const float* __restrict__ W_attn, const float* __restrict__ b_attn,
                 const float* __restrict__ Sp, const float* __restrict__ W_proj,
                 unsigned short* __restrict__ Bt2, unsigned short* __restrict__ WpT,
                 float* __restrict__ bias2) {
  __shared__ float shmem[2048];
  const int bid = blockIdx.x;
  const int tid = threadIdx.x;

  if (bid < 512) {                      // ---- cvt4: hidden -> hB ----
    const int n4 = (B_ * S_ * D_) / 4;
    int i = bid * 256 + tid;
    for (; i < n4; i += 512 * 256) {
      float4 v = *(const float4*)(hidden + 4 * (size_t)i);
      short4v o = {(short)f2b(v.x), (short)f2b(v.y), (short)f2b(v.z), (short)f2b(v.w)};
      *(short4v*)(hB + 4 * (size_t)i) = o;
    }
  } else if (bid < 2560) {              // ---- tcvt: 32x32 transpose-convert tiles ----
    const float* in;
    unsigned short* out;
    int Cs, local;
    if (bid < 1536) { local = bid - 512;  in = W_attn + 2048; out = Bt2 + 1024 * 1024; Cs = N3; }
    else            { local = bid - 1536; in = W_proj;        out = WpT;               Cs = D_; }
    float (*t)[33] = (float(*)[33])shmem;
    int c0 = (local & 31) * 32, r0 = (local >> 5) * 32;
    int tx = tid & 31, ty = tid >> 5;
    for (int j = 0; j < 32; j += 8)
      t[ty + j][tx] = in[(size_t)(r0 + ty + j) * Cs + c0 + tx];
    __syncthreads();
    for (int j = 0; j < 32; j += 8)
      out[(size_t)(c0 + ty + j) * D_ + r0 + tx] = f2b(t[tx][ty + j]);
  } else {                              // ---- wjl: fused JL weights ----
    const int lb = bid - 2560;          // 0..127
    const int part = lb >> 6;           // 0 = Q, 1 = K
    const int h = (lb >> 2) & 15;
    const int dc = lb & 3;
    for (int i = tid; i < 32 * 64; i += 256) shmem[i] = Sp[i];
    __syncthreads();
    const float scale = part ? 1.0f : 0.125f * 1.44269504f;
    const int d = dc * 256 + tid;
    float w[64];
    const float* src = W_attn + (size_t)d * N3 + part * D_ + h * 64;
    for (int j = 0; j < 16; ++j) {
      float4 v = *(const float4*)&src[j * 4];
      w[j * 4 + 0] = v.x; w[j * 4 + 1] = v.y; w[j * 4 + 2] = v.z; w[j * 4 + 3] = v.w;
    }
    const int nbase = part * 512 + h * 32;
    for (int kjl = 0; kjl < 32; ++kjl) {
      float acc = 0.f;
      for (int hd = 0; hd < 64; ++hd) acc += w[hd] * shmem[kjl * 64 + hd];
      Bt2[(size_t)(nbase + kjl) * D_ + d] = f2b(acc * scale);
    }
    if (dc == 0 && tid < 32) {
      float acc = 0.f;
      for (int hd = 0; hd < 64; ++hd) acc += b_attn[part * D_ + h * 64 + hd] * shmem[tid * 64 + hd];
      bias2[nbase + tid] = acc * scale;
    }
  }
}

// ---------------- fused qkv+JL GEMM: 128x128 tiles, BK=64 ----------------
__global__ __launch_bounds__(256, 2)
void qkv2_gemm_kernel(const unsigned short* __restrict__ A,
                      const unsigned short* __restrict__ Bt,
                      const float* __restrict__ b_attn,
                      const float* __restrict__ bias2,
                      unsigned short* __restrict__ Qjl,
                      unsigned short* __restrict__ Kjl,
                      unsigned short* __restrict__ Vc) {
  __shared__ __align__(16) unsigned short As[2][128 * 32];
  __shared__ __align__(16) unsigned short Bs[2][128 * 32];
  const int tid = threadIdx.x;
  const int lane = tid & 63, wv = tid >> 6;
  const int quad = lane >> 4, col = lane & 15;
  const int wm = wv >> 1, wn = wv & 1;
  const int m0 = blockIdx.y * 128, n0 = blockIdx.x * 128;

  floatx4 acc[4][4] = {};

  for (int kk = 0; kk < D_; kk += 64) {
    for (int it = 0; it < 4; ++it) {
      int c = it * 256 + tid;            // 0..1023
      int ks = c >> 9, row = (c >> 2) & 127, kc = c & 3;
      async16(A + (size_t)(m0 + row) * D_ + kk + ks * 32 + kc * 8,
              (unsigned short*)As + c * 8);
    }
    for (int it = 0; it < 4; ++it) {
      int c = it * 256 + tid;
      int ks = c >> 9, row = (c >> 2) & 127, kc = c & 3;
      async16(Bt + (size_t)(n0 + row) * D_ + kk + ks * 32 + kc * 8,
              (unsigned short*)Bs + c * 8);
    }
    asm volatile("s_waitcnt vmcnt(0)" ::: "memory");
    __syncthreads();
    for (int ks = 0; ks < 2; ++ks) {
      bf16x8 af[4], bfr[4];
      for (int mt = 0; mt < 4; ++mt)
        af[mt] = *(const bf16x8*)&As[ks][(wm * 64 + mt * 16 + col) * 32 + quad * 8];
      for (int nt = 0; nt < 4; ++nt)
        bfr[nt] = *(const bf16x8*)&Bs[ks][(wn * 64 + nt * 16 + col) * 32 + quad * 8];
      for (int mt = 0; mt < 4; ++mt)
        for (int nt = 0; nt < 4; ++nt)
          acc[mt][nt] = __builtin_amdgcn_mfma_f32_16x16x32_bf16(
              af[mt], bfr[nt], acc[mt][nt], 0, 0, 0);
    }
    __syncthreads();
  }

  const int pq = n0 >> 9;  // 0=Q, 1=K, >=2 -> V
  for (int mt = 0; mt < 4; ++mt) {
    int gm0 = m0 + wm * 64 + mt * 16 + quad * 4;
    int b = gm0 >> 11, s = gm0 & (S_ - 1);
    for (int nt = 0; nt < 4; ++nt) {
      int gn = n0 + wn * 64 + nt * 16 + col;
      if (pq >= 2) {
        int vcol = gn - 1024;
        float bs = b_attn[2048 + vcol];
        int h = vcol >> 6, hd = vcol & 63;
        short4v vv;
        for (int i = 0; i < 4; ++i)
          vv[i] = (short)f2b(acc[mt][nt][i] + bs);
        size_t idx = ((((size_t)(b * H_ + h) * 64 + (s >> 5)) * 64 + hd) * 32 + (s & 31));
        *(short4v*)&Vc[idx] = vv;
      } else {
        float bs = bias2[gn];
        int gl = gn & 511;
        int h = gl >> 5, kjl = gl & 31;
        unsigned short* dst = pq ? Kjl : Qjl;
        size_t base = ((size_t)(b * H_ + h) * S_ + s) * KJL + kjl;
        for (int i = 0; i < 4; ++i)
          dst[base + (size_t)i * KJL] = f2b(acc[mt][nt][i] + bs);
      }
    }
  }
}

// ---------------- split-2-within-block flash attention (LDS merge, no fences) ----------------
// Block = 4 waves = 2 q-tiles x 2 K-halves. Fixed-max softmax => partials additive;
// halves exchange through LDS + __syncthreads. The two tiles in a block share the
// same g (equal trip counts), and g = (u&8) ? 15-a : a makes the 4 co-resident
// blocks/CU sum to a CONSTANT 9 chunks of work.
// LESSONS ENCODED: round 11's in-kernel global merge (__threadfence + device atomic)
// cost ~170 us in cross-XCD L2 writeback stalls — never fence/merge through global
// inside a kernel; the kernel boundary or LDS is the cheap path. Round 8: don't cap
// launch_bounds min-waves (VGPR 64 -> 415 MB spills). Round 5: no runtime-indexed
// register arrays.
__global__ __launch_bounds__(256, 2)
void attn_kernel(const unsigned short* __restrict__ Qjl,
                 const unsigned short* __restrict__ Kjl,
                 const unsigned short* __restrict__ Vc,
                 unsigned short* __restrict__ AO) {
  __shared__ __align__(16) unsigned short Ps[4][32 * 136];  // wave-private strips, 8704 B each
  const int tid = threadIdx.x;
  const int lane = tid & 63, wv = tid >> 6;
  const int quad = lane >> 4, l15 = lane & 15;

  const int blk = blockIdx.x;            // 0..1023
  const int bh = blk & 31;               // bh ≡ xcd (mod 8): L2 locality
  const int u = blk >> 5;                // 0..31
  const int a = u & 7;
  const int g = (u & 8) ? (15 - a) : a;  // co-resident blocks: work(a)+work(15-a)=9 const
  const int rp = (u >> 4) & 1;
  const int pairid = wv >> 1;            // which of the block's 2 tiles
  const int half = wv & 1;               // which K-half this wave computes
  const int t = g * 4 + rp * 2 + pairid; // q-tile: rows t*32..t*32+31
  const int b = bh >> 4, h = bh & 15;

  unsigned short* Pw = &Ps[wv][0];
  const int nch = g + 1;                 // chunks for this tile (t>>2 == g)
  const int kb = half ? ((nch + 1) >> 1) : 0;
  const int ke = half ? nch : ((nch + 1) >> 1);
  const int lastc = nch - 1;
  const int r = t & 3;

  const int laneK = l15 * KJL + quad * 8;
  const int laneV = l15 * 32 + quad * 8;
  const unsigned short* Kp = Kjl + (size_t)bh * S_ * KJL + laneK + (size_t)kb * 128 * KJL;
  const unsigned short* Vp = Vc + (size_t)bh * (64 * 64 * 32) + laneV + (size_t)kb * 8192;

  bf16x8 aq[2];
  for (int qn = 0; qn < 2; ++qn)
    aq[qn] = *(const bf16x8*)&Qjl[(size_t)(bh * S_ + t * 32 + qn * 16 + l15) * KJL + quad * 8];

  floatx4 o[4][2] = {};
  floatx4 psum[2] = {};
  const floatx4 zz = {0.f, 0.f, 0.f, 0.f};

  for (int kt = kb; kt < ke; ++kt) {
    bf16x8 ak[8];
    for (int sm = 0; sm < 8; ++sm)
      ak[sm] = *(const bf16x8*)&Kp[sm * (16 * KJL)];
    bf16x8 bv[4][4];
    for (int ks = 0; ks < 4; ++ks)
      for (int md = 0; md < 4; ++md)
        bv[ks][md] = *(const bf16x8*)&Vp[ks * 2048 + md * 512];
    Kp += 128 * KJL;
    Vp += 8192;

    floatx4 sc[8][2];
    for (int sm = 0; sm < 8; ++sm)
      for (int qn = 0; qn < 2; ++qn)
        sc[sm][qn] = __builtin_amdgcn_mfma_f32_16x16x32_bf16(ak[sm], aq[qn], zz, 0, 0, 0);

    if (kt == lastc) {                   // causal mask within final chunk
      for (int qn = 0; qn < 2; ++qn) {
        int qloc = r * 32 + qn * 16 + l15;
        for (int sm = 0; sm < 8; ++sm)
          for (int i = 0; i < 4; ++i)
            if (sm * 16 + quad * 4 + i > qloc) sc[sm][qn][i] = -1e30f;
      }
    }

    for (int qn = 0; qn < 2; ++qn) {
      for (int sm = 0; sm < 8; ++sm) {
        float p0 = __builtin_amdgcn_exp2f(sc[sm][qn][0]);
        float p1 = __builtin_amdgcn_exp2f(sc[sm][qn][1]);
        float p2 = __builtin_amdgcn_exp2f(sc[sm][qn][2]);
        float p3 = __builtin_amdgcn_exp2f(sc[sm][qn][3]);
        psum[qn][0] += p0; psum[qn][1] += p1;
        psum[qn][2] += p2; psum[qn][3] += p3;
        uint2v pk2 = {pkbf(p0, p1), pkbf(p2, p3)};
        *(uint2v*)&Pw[(qn * 16 + l15) * 136 + sm * 16 + quad * 4] = pk2;
      }
    }

    for (int ks = 0; ks < 4; ++ks) {
      bf16x8 bp[2];
      for (int qn = 0; qn < 2; ++qn)
        bp[qn] = *(const bf16x8*)&Pw[(qn * 16 + l15) * 136 + ks * 32 + quad * 8];
      for (int qn = 0; qn < 2; ++qn)
        for (int md = 0; md < 4; ++md)
          o[md][qn] = __builtin_amdgcn_mfma_f32_16x16x32_bf16(bv[ks][md], bp[qn], o[md][qn], 0, 0, 0);
    }
  }

  // ---- reduce row sums ----
  float l0 = psum[0][0] + psum[0][1] + psum[0][2] + psum[0][3];
  float l1 = psum[1][0] + psum[1][1] + psum[1][2] + psum[1][3];
  l0 += __shfl_xor(l0, 16, 64); l0 += __shfl_xor(l0, 32, 64);
  l1 += __shfl_xor(l1, 16, 64); l1 += __shfl_xor(l1, 32, 64);

  // ---- half 1 publishes its partial into its own LDS strip (fp32 overlay) ----
  if (half) {
    float* fp = (float*)Pw;              // 2176 floats = 8704 B, exactly the strip
    for (int qn = 0; qn < 2; ++qn)
      for (int md = 0; md < 4; ++md)
        *(floatx4*)(fp + (qn * 4 + md) * 256 + lane * 4) = o[md][qn];
    fp[2048 + lane] = l0;
    fp[2112 + lane] = l1;
  }
  __syncthreads();

  // ---- half 0 merges partner's partial, normalizes, transposes, writes AO ----
  if (!half) {
    const float* fq = (const float*)(&Ps[wv | 1][0]);
    float inv0 = 1.f / (l0 + fq[2048 + lane]);
    float inv1 = 1.f / (l1 + fq[2112 + lane]);
    for (int qn = 0; qn < 2; ++qn) {
      float inv = qn ? inv1 : inv0;
      for (int md = 0; md < 4; ++md) {
        floatx4 p = *(const floatx4*)(fq + (qn * 4 + md) * 256 + lane * 4);
        floatx4 s = o[md][qn];
        uint2v t4 = {pkbf((s[0] + p[0]) * inv, (s[1] + p[1]) * inv),
                     pkbf((s[2] + p[2]) * inv, (s[3] + p[3]) * inv)};
        *(uint2v*)&Pw[(qn * 16 + l15) * 72 + md * 16 + quad * 4] = t4;
      }
    }
    asm volatile("s_waitcnt lgkmcnt(0)" ::: "memory");
    int q = lane >> 1, hf = lane & 1;
    size_t gbase = ((size_t)(b * S_ + t * 32 + q)) * D_ + h * HD_ + hf * 32;
    for (int jj = 0; jj < 4; ++jj) {
      bf16x8 v = *(const bf16x8*)&Pw[q * 72 + hf * 32 + jj * 8];
      *(bf16x8*)&AO[gbase + jj * 8] = v;
    }
  }
}

// ---------------- output projection: 64x128 tiles, BK=64 ----------------
__global__ __launch_bounds__(256, 2)
void proj_gemm_kernel(const unsigned short* __restrict__ A,
                      const unsigned short* __restrict__ Bt,
                      const float* __restrict__ bias,
                      float* __restrict__ out) {
  __shared__ __align__(16) unsigned short As[2][64 * 32];
  __shared__ __align__(16) unsigned short Bs[2][128 * 32];
  const int tid = threadIdx.x;
  const int lane = tid & 63, wv = tid >> 6;
  const int quad = lane >> 4, col = lane & 15;
  const int wm = wv >> 1, wn = wv & 1;
  const int m0 = blockIdx.y * 64, n0 = blockIdx.x * 128;

  floatx4 acc[2][4] = {};

  for (int kk = 0; kk < D_; kk += 64) {
    for (int it = 0; it < 2; ++it) {     // A: 64 rows x 64 k = 512 chunks
      int c = it * 256 + tid;
      int ks = c >> 8, row = (c >> 2) & 63, kc = c & 3;
      async16(A + (size_t)(m0 + row) * D_ + kk + ks * 32 + kc * 8,
              (unsigned short*)As + c * 8);
    }
    for (int it = 0; it < 4; ++it) {     // B: 128 rows x 64 k = 1024 chunks
      int c = it * 256 + tid;
      int ks = c >> 9, row = (c >> 2) & 127, kc = c & 3;
      async16(Bt + (size_t)(n0 + row) * D_ + kk + ks * 32 + kc * 8,
              (unsigned short*)Bs + c * 8);
    }
    asm volatile("s_waitcnt vmcnt(0)" ::: "memory");
    __syncthreads();
    for (int ks = 0; ks < 2; ++ks) {
      bf16x8 af[2], bfr[4];
      for (int mt = 0; mt < 2; ++mt)
        af[mt] = *(const bf16x8*)&As[ks][(wm * 32 + mt * 16 + col) * 32 + quad * 8];
      for (int nt = 0; nt < 4; ++nt)
        bfr[nt] = *(const bf16x8*)&Bs[ks][(wn * 64 + nt * 16 + col) * 32 + quad * 8];
      for (int mt = 0; mt < 2; ++mt)
        for (int nt = 0; nt < 4; ++nt)
          acc[mt][nt] = __builtin_amdgcn_mfma_f32_16x16x32_bf16(
              af[mt], bfr[nt], acc[mt][nt], 0, 0, 0);
    }
    __syncthreads();
  }

  for (int mt = 0; mt < 2; ++mt) {
    int gm0 = m0 + wm * 32 + mt * 16 + quad * 4;
    for (int nt = 0; nt < 4; ++nt) {
      int gn = n0 + wn * 64 + nt * 16 + col;
      float bs = bias[gn];
      for (int i = 0; i < 4; ++i)
        out[(size_t)(gm0 + i) * D_ + gn] = acc[mt][nt][i] + bs;
    }
  }
}

extern "C" void kernel_launch(void* const* d_in, const int* in_sizes, int n_in,
                              void* d_out, int out_size, void* d_ws, size_t ws_size,
                              hipStream_t stream) {
  (void)in_sizes; (void)n_in; (void)out_size; (void)ws_size;
  const float* hidden = (const float*)d_in[0];
  const float* W_attn = (const float*)d_in[1];
  const float* b_attn = (const float*)d_in[2];
  const float* S_proj = (const float*)d_in[3];
  const float* W_proj = (const float*)d_in[4];
  const float* b_proj = (const float*)d_in[5];
  float* out = (float*)d_out;

  char* ws = (char*)d_ws;
  unsigned short* hB    = (unsigned short*)(ws);                    //  8 MB
  unsigned short* Bt2   = (unsigned short*)(ws + (8u << 20));       //  4 MB
  unsigned short* WpT   = (unsigned short*)(ws + (12u << 20));      //  2 MB
  float*          bias2 = (float*)         (ws + (14u << 20));      //  4 KB
  unsigned short* Qjl   = (unsigned short*)(ws + (15u << 20));      //  4 MB
  unsigned short* Kjl   = (unsigned short*)(ws + (19u << 20));      //  4 MB
  unsigned short* Vc    = (unsigned short*)(ws + (23u << 20));      //  8 MB
  unsigned short* AO    = (unsigned short*)(ws + (31u << 20));      //  8 MB

  prep_kernel<<<2688, 256, 0, stream>>>(hidden, hB, W_attn, b_attn, S_proj,
                                        W_proj, Bt2, WpT, bias2);
  qkv2_gemm_kernel<<<dim3(N2 / 128, (B_ * S_) / 128), 256, 0, stream>>>(
      hB, Bt2, b_attn, bias2, Qjl, Kjl, Vc);
  attn_kernel<<<1024, 256, 0, stream>>>(Qjl, Kjl, Vc, AO);
  proj_gemm_kernel<<<dim3(D_ / 128, (B_ * S_) / 64), 256, 0, stream>>>(
      AO, WpT, b_proj, out);
}